// Round 6
// baseline (126.921 us; speedup 1.0000x reference)
//
#include <hip/hip_runtime.h>

typedef __attribute__((ext_vector_type(8))) _Float16 half8;
typedef __attribute__((ext_vector_type(4))) _Float16 half4;
typedef __attribute__((ext_vector_type(4))) float f32x4;

#define NB 2
#define CIN 64
#define ICH 32
#define HH 80
#define WW 80
#define NSP 6400
#define KSPLIT 5
#define KRANGE 1280
#define KBLK 64
#define NITER 20
#define QBLK 16
#define QTILES 400

// ---------------------------------------------------------------------------
// Kernel 0: weight prep. W9f[tap][o][c] f16, GWf[o][c] f16.
// ---------------------------------------------------------------------------
__global__ __launch_bounds__(256) void nlb_prep_kernel(
    const float* __restrict__ shared_w, const float* __restrict__ g_w,
    _Float16* __restrict__ W9f, _Float16* __restrict__ GWf)
{
    int e = blockIdx.x * 256 + threadIdx.x;
    if (e < 9 * 32 * 64) {
        int c = e & 63, o = (e >> 6) & 31, tap = e >> 11;
        W9f[e] = (_Float16)shared_w[(o * 64 + c) * 9 + tap];
    } else {
        int e2 = e - 9 * 32 * 64;
        GWf[e2] = (_Float16)g_w[e2];
    }
}

// ---------------------------------------------------------------------------
// Kernel 1: implicit-GEMM 3x3 conv via MFMA + fused 1x1 g-conv (round-2 proven).
// ---------------------------------------------------------------------------
__global__ __launch_bounds__(128) void nlb_conv_mfma_kernel(
    const float* __restrict__ x, const float* __restrict__ x_t,
    const _Float16* __restrict__ W9f, const _Float16* __restrict__ GWf,
    const float* __restrict__ shared_b, const float* __restrict__ g_b,
    _Float16* __restrict__ Q, _Float16* __restrict__ K, _Float16* __restrict__ Vt)
{
    const int bid = blockIdx.x;
    const int src = bid & 1;
    const int b   = (bid >> 1) & 1;
    const int h   = bid >> 2;
    const float* __restrict__ in = src ? x_t : x;

    __shared__ _Float16 xs[3 * 82 * 64];

    const int tid = threadIdx.x;

    #pragma unroll
    for (int i = 0; i < 15; ++i) {
        int idx = tid + i * 128;
        int wc = idx % 10;
        int c  = (idx / 10) & 63;
        int rr = idx / 640;
        int hr = h + rr - 1;
        float4 v0 = make_float4(0.f, 0.f, 0.f, 0.f), v1 = v0;
        if (hr >= 0 && hr < HH) {
            const float4* p = (const float4*)(in + ((size_t)(b * CIN + c) * HH + hr) * WW + wc * 8);
            v0 = p[0]; v1 = p[1];
        }
        float vals[8] = {v0.x, v0.y, v0.z, v0.w, v1.x, v1.y, v1.z, v1.w};
        const int cb = c >> 3, cl = c & 7;
        #pragma unroll
        for (int k = 0; k < 8; ++k) {
            int wi = wc * 8 + k + 1;
            int slot = cb ^ ((wi + (wi >> 3)) & 7);
            xs[(rr * 82 + wi) * 64 + slot * 8 + cl] = (_Float16)vals[k];
        }
    }
    for (int e = tid; e < 384; e += 128) {
        int wi = (e & 1) ? 81 : 0;
        int rest = e >> 1;
        int c = rest & 63, rr = rest >> 6;
        int slot = (c >> 3) ^ ((wi + (wi >> 3)) & 7);
        xs[(rr * 82 + wi) * 64 + slot * 8 + (c & 7)] = (_Float16)0.f;
    }
    __syncthreads();

    const int wid  = tid >> 6;
    const int lane = tid & 63;
    const int g = lane >> 4, r = lane & 15;
    const int o0 = wid * 16;

    half8 aw[9][2];
    #pragma unroll
    for (int tap = 0; tap < 9; ++tap)
        #pragma unroll
        for (int ch = 0; ch < 2; ++ch)
            aw[tap][ch] = *(const half8*)(W9f + ((tap * 32 + o0 + r) * 64 + ch * 32 + g * 8));
    half8 gaf[2];
    if (src) {
        #pragma unroll
        for (int ch = 0; ch < 2; ++ch)
            gaf[ch] = *(const half8*)(GWf + ((o0 + r) * 64 + ch * 32 + g * 8));
    }

    f32x4 biasv, gbv = {0.f, 0.f, 0.f, 0.f};
    #pragma unroll
    for (int j = 0; j < 4; ++j) biasv[j] = shared_b[o0 + g * 4 + j];
    if (src) {
        #pragma unroll
        for (int j = 0; j < 4; ++j) gbv[j] = g_b[o0 + g * 4 + j];
    }

    for (int ti = 0; ti < 5; ++ti) {
        const int n0 = ti * 16;
        const int wi0 = n0 + r;
        f32x4 accE = biasv;
        f32x4 accO = {0.f, 0.f, 0.f, 0.f};
        f32x4 vacc = gbv;
        #pragma unroll
        for (int tap = 0; tap < 9; ++tap) {
            const int kh = tap / 3, kw = tap % 3;
            const int wi = wi0 + kw;
            const int swz = (wi + (wi >> 3)) & 7;
            #pragma unroll
            for (int ch = 0; ch < 2; ++ch) {
                half8 bf = *(const half8*)(&xs[(kh * 82 + wi) * 64 + (((ch * 4 + g) ^ swz) * 8)]);
                if (tap & 1) accO = __builtin_amdgcn_mfma_f32_16x16x32_f16(aw[tap][ch], bf, accO, 0, 0, 0);
                else         accE = __builtin_amdgcn_mfma_f32_16x16x32_f16(aw[tap][ch], bf, accE, 0, 0, 0);
                if (src && tap == 4)
                    vacc = __builtin_amdgcn_mfma_f32_16x16x32_f16(gaf[ch], bf, vacc, 0, 0, 0);
            }
        }
        const int n = h * WW + n0 + r;
        f32x4 acc;
        #pragma unroll
        for (int j = 0; j < 4; ++j) acc[j] = accE[j] + accO[j];
        half4 pk;
        #pragma unroll
        for (int j = 0; j < 4; ++j) pk[j] = (_Float16)acc[j];
        if (!src) {
            *(half4*)(Q + (size_t)(b * NSP + n) * ICH + o0 + g * 4) = pk;
        } else {
            *(half4*)(K + (size_t)(b * NSP + n) * ICH + o0 + g * 4) = pk;
            #pragma unroll
            for (int j = 0; j < 4; ++j)
                Vt[(size_t)(b * ICH + o0 + g * 4 + j) * NSP + n] = (_Float16)vacc[j];
        }
    }
}

// ---------------------------------------------------------------------------
// Kernel 2: flash attention, fully register-resident (no LDS, no barriers).
// S^T = mfma_16x16x32(K,Q) leaves P in exactly the B-fragment layout of
// mfma_16x16x16, so PV consumes P directly: y^T[d][q] += V16[kh] x P16[kh].
// All of lane's 8 y-values belong to q=lane&15 -> rescale needs no shuffles.
// grid = 4000 x 64 (one wave per (b, 16-q-tile, k-split)).
// ---------------------------------------------------------------------------
#define ATTN_BODY(IT, KCUR, KNXT)                                              \
  {                                                                            \
    const int it_ = (IT);                                                      \
    const int itn_ = (it_ + 1 < NITER) ? it_ + 1 : it_;                        \
    const _Float16* Kn_ = Kb + (size_t)itn_ * KBLK * ICH;                      \
    _Pragma("unroll")                                                          \
    for (int kh = 0; kh < 4; ++kh)                                             \
      KNXT[kh] = *(const half8*)(Kn_ + (kh * 16 + r) * ICH + g * 8);           \
    const _Float16* Vc_ = Vb + it_ * KBLK;                                     \
    half4 vf[4][2];                                                            \
    _Pragma("unroll")                                                          \
    for (int kh = 0; kh < 4; ++kh)                                             \
      _Pragma("unroll")                                                        \
      for (int ch = 0; ch < 2; ++ch)                                           \
        vf[kh][ch] = *(const half4*)(Vc_ + (size_t)(ch * 16 + r) * NSP + kh * 16 + g * 4); \
    f32x4 sa[4];                                                               \
    _Pragma("unroll")                                                          \
    for (int kh = 0; kh < 4; ++kh)                                             \
      sa[kh] = __builtin_amdgcn_mfma_f32_16x16x32_f16(KCUR[kh], qa, zero4, 0, 0, 0); \
    float vmax = fmaxf(fmaxf(fmaxf(sa[0][0], sa[0][1]), fmaxf(sa[0][2], sa[0][3])),      \
                       fmaxf(fmaxf(sa[1][0], sa[1][1]), fmaxf(sa[1][2], sa[1][3])));     \
    vmax = fmaxf(vmax, fmaxf(fmaxf(fmaxf(sa[2][0], sa[2][1]), fmaxf(sa[2][2], sa[2][3])),\
                             fmaxf(fmaxf(sa[3][0], sa[3][1]), fmaxf(sa[3][2], sa[3][3]))));\
    if (__any(vmax - m2 > 8.f)) {                                              \
      float tm = vmax;                                                         \
      tm = fmaxf(tm, __shfl_xor(tm, 16));                                      \
      tm = fmaxf(tm, __shfl_xor(tm, 32));                                      \
      float mn = fmaxf(m2, tm);                                                \
      float sc = __expf(m2 - mn);                                              \
      m2 = mn; lp *= sc;                                                       \
      _Pragma("unroll")                                                        \
      for (int j = 0; j < 4; ++j) { yacc[0][j] *= sc; yacc[1][j] *= sc; }      \
    }                                                                          \
    half4 pk[4];                                                               \
    _Pragma("unroll")                                                          \
    for (int kh = 0; kh < 4; ++kh) {                                           \
      float ls = 0.f;                                                          \
      _Pragma("unroll")                                                        \
      for (int j = 0; j < 4; ++j) {                                            \
        float p = __expf(sa[kh][j] - m2);                                      \
        ls += p; pk[kh][j] = (_Float16)p;                                      \
      }                                                                        \
      lp += ls;                                                                \
    }                                                                          \
    _Pragma("unroll")                                                          \
    for (int kh = 0; kh < 4; ++kh)                                             \
      _Pragma("unroll")                                                        \
      for (int ch = 0; ch < 2; ++ch)                                           \
        yacc[ch] = __builtin_amdgcn_mfma_f32_16x16x16f16(                      \
            vf[kh][ch], pk[kh], yacc[ch], 0, 0, 0);                            \
  }

__global__ __launch_bounds__(64) void nlb_attn_kernel(
    const _Float16* __restrict__ Q, const _Float16* __restrict__ Km,
    const _Float16* __restrict__ Vt,
    float* __restrict__ YU, float* __restrict__ ML)
{
    const int bid = blockIdx.x;
    const int s = bid % KSPLIT;
    const int t = (bid / KSPLIT) % QTILES;
    const int b = bid / (KSPLIT * QTILES);
    const int lane = threadIdx.x;
    const int g = lane >> 4, r = lane & 15;

    const _Float16* __restrict__ Qb = Q  + (size_t)b * NSP * ICH;
    const _Float16* __restrict__ Kb = Km + (size_t)b * NSP * ICH + (size_t)s * KRANGE * ICH;
    const _Float16* __restrict__ Vb = Vt + (size_t)b * ICH * NSP + s * KRANGE;

    const f32x4 zero4 = {0.f, 0.f, 0.f, 0.f};

    half8 qa = *(const half8*)(Qb + (size_t)(t * QBLK + r) * ICH + g * 8);

    f32x4 yacc[2];
    yacc[0] = zero4; yacc[1] = zero4;
    float m2 = -1e30f, lp = 0.f;

    half8 kfA[4], kfB[4];
    #pragma unroll
    for (int kh = 0; kh < 4; ++kh)
        kfA[kh] = *(const half8*)(Kb + (kh * 16 + r) * ICH + g * 8);

    for (int ith = 0; ith < NITER; ith += 2) {
        ATTN_BODY(ith, kfA, kfB)
        ATTN_BODY(ith + 1, kfB, kfA)
    }

    // epilogue: reduce l across the 4 g-copies of each q; write ML + f32 y^T
    float lv = lp;
    lv += __shfl_xor(lv, 16);
    lv += __shfl_xor(lv, 32);
    if (g == 0) {
        size_t base = ((size_t)(s * NB + b) * NSP + t * QBLK + r) * 2;
        ML[base + 0] = m2;
        ML[base + 1] = lv;
    }
    // lane (g,r) holds y[q = t*QBLK + r][d = ch*16 + g*4 + j]
    #pragma unroll
    for (int ch = 0; ch < 2; ++ch)
        *(f32x4*)(YU + ((size_t)(s * NB + b) * NSP + t * QBLK + r) * ICH
                  + ch * 16 + g * 4) = yacc[ch];
}

// ---------------------------------------------------------------------------
// Kernel 3: combine k-splits, normalize, fused W 1x1 projection + bias +
// residual (round-2 proven verbatim). grid = 200 x 256.
// ---------------------------------------------------------------------------
__global__ __launch_bounds__(256) void nlb_combine_kernel(
    const float* __restrict__ YU, const float* __restrict__ ML,
    const float* __restrict__ W_w, const float* __restrict__ W_b,
    const float* __restrict__ x, float* __restrict__ out)
{
    const int bid = blockIdx.x;
    const int b = bid / 100;
    const int rowbase = (bid % 100) * 64;

    __shared__ float ylds[64][33];
    __shared__ float wwl[CIN * ICH];

    const int tid = threadIdx.x;
    for (int e = tid; e < CIN * ICH; e += 256) wwl[e] = W_w[e];

    #pragma unroll
    for (int i = 0; i < 8; ++i) {
        int idx = tid + i * 256;
        int row = idx >> 5, c = idx & 31;
        int grow = rowbase + row;
        float m[KSPLIT], lv[KSPLIT], M = -1e30f;
        #pragma unroll
        for (int s2 = 0; s2 < KSPLIT; ++s2) {
            size_t base = ((size_t)(s2 * NB + b) * NSP + grow) * 2;
            m[s2]  = ML[base + 0];
            lv[s2] = ML[base + 1];
            M = fmaxf(M, m[s2]);
        }
        float denom = 0.f, acc = 0.f;
        #pragma unroll
        for (int s2 = 0; s2 < KSPLIT; ++s2) {
            float e2 = __expf(m[s2] - M);
            denom += lv[s2] * e2;
            acc += YU[((size_t)(s2 * NB + b) * NSP + grow) * ICH + c] * e2;
        }
        ylds[row][c] = acc / denom;
    }
    __syncthreads();

    const int row = tid & 63;
    const int o0  = tid >> 6;
    #pragma unroll
    for (int k = 0; k < 16; ++k) {
        int o = o0 * 16 + k;
        size_t gi = (size_t)(b * CIN + o) * NSP + rowbase + row;
        float accv = W_b[o] + x[gi];
        #pragma unroll
        for (int c = 0; c < ICH; ++c) accv += wwl[o * ICH + c] * ylds[row][c];
        out[gi] = accv;
    }
}

// ---------------------------------------------------------------------------
extern "C" void kernel_launch(void* const* d_in, const int* in_sizes, int n_in,
                              void* d_out, int out_size, void* d_ws, size_t ws_size,
                              hipStream_t stream) {
    const float* x        = (const float*)d_in[0];
    const float* x_t      = (const float*)d_in[1];
    const float* g_w      = (const float*)d_in[2];
    const float* g_b      = (const float*)d_in[3];
    const float* W_w      = (const float*)d_in[4];
    const float* W_b      = (const float*)d_in[5];
    const float* shared_w = (const float*)d_in[6];
    const float* shared_b = (const float*)d_in[7];
    float* out = (float*)d_out;

    char* ws = (char*)d_ws;
    _Float16* Q   = (_Float16*)(ws);                   //   819,200 B
    _Float16* K   = (_Float16*)(ws + 819200);          //   819,200 B
    _Float16* Vt  = (_Float16*)(ws + 1638400);         //   819,200 B
    float*    YU  = (float*)(ws + 2457600);            // 8,192,000 B (f32 unnormalized)
    float*    ML  = (float*)(ws + 10649600);           //   512,000 B
    _Float16* W9f = (_Float16*)(ws + 11161600);        //    36,864 B
    _Float16* GWf = (_Float16*)(ws + 11198464);        //     4,096 B  (total ~11.2 MB)

    hipLaunchKernelGGL(nlb_prep_kernel, dim3(80), dim3(256), 0, stream,
                       shared_w, g_w, W9f, GWf);
    hipLaunchKernelGGL(nlb_conv_mfma_kernel, dim3(320), dim3(128), 0, stream,
                       x, x_t, W9f, GWf, shared_b, g_b, Q, K, Vt);
    hipLaunchKernelGGL(nlb_attn_kernel, dim3(NB * QTILES * KSPLIT), dim3(64), 0, stream,
                       Q, K, Vt, YU, ML);
    hipLaunchKernelGGL(nlb_combine_kernel, dim3(200), dim3(256), 0, stream,
                       YU, ML, W_w, W_b, x, out);
}

// Round 7
// 90.583 us; speedup vs baseline: 1.4012x; 1.4012x over previous
//
#include <hip/hip_runtime.h>

typedef __attribute__((ext_vector_type(8))) _Float16 half8;
typedef __attribute__((ext_vector_type(4))) _Float16 half4;
typedef __attribute__((ext_vector_type(4))) float f32x4;

#define NB 2
#define CIN 64
#define ICH 32
#define HH 80
#define WW 80
#define NSP 6400
#define KSPLIT 5
#define KRANGE 1280
#define KBLK 64
#define NITER 20
#define QBLK 32
#define QTILES 200

// ---------------------------------------------------------------------------
// Kernel 0: weight prep. W9f[tap][o][c] f16, GWf[o][c] f16.
// ---------------------------------------------------------------------------
__global__ __launch_bounds__(256) void nlb_prep_kernel(
    const float* __restrict__ shared_w, const float* __restrict__ g_w,
    _Float16* __restrict__ W9f, _Float16* __restrict__ GWf)
{
    int e = blockIdx.x * 256 + threadIdx.x;
    if (e < 9 * 32 * 64) {
        int c = e & 63, o = (e >> 6) & 31, tap = e >> 11;
        W9f[e] = (_Float16)shared_w[(o * 64 + c) * 9 + tap];
    } else {
        int e2 = e - 9 * 32 * 64;
        GWf[e2] = (_Float16)g_w[e2];
    }
}

// ---------------------------------------------------------------------------
// Kernel 1: implicit-GEMM 3x3 conv via MFMA + fused 1x1 g-conv (round-2 proven).
// ---------------------------------------------------------------------------
__global__ __launch_bounds__(128) void nlb_conv_mfma_kernel(
    const float* __restrict__ x, const float* __restrict__ x_t,
    const _Float16* __restrict__ W9f, const _Float16* __restrict__ GWf,
    const float* __restrict__ shared_b, const float* __restrict__ g_b,
    _Float16* __restrict__ Q, _Float16* __restrict__ K, _Float16* __restrict__ Vt)
{
    const int bid = blockIdx.x;
    const int src = bid & 1;
    const int b   = (bid >> 1) & 1;
    const int h   = bid >> 2;
    const float* __restrict__ in = src ? x_t : x;

    __shared__ _Float16 xs[3 * 82 * 64];

    const int tid = threadIdx.x;

    #pragma unroll
    for (int i = 0; i < 15; ++i) {
        int idx = tid + i * 128;
        int wc = idx % 10;
        int c  = (idx / 10) & 63;
        int rr = idx / 640;
        int hr = h + rr - 1;
        float4 v0 = make_float4(0.f, 0.f, 0.f, 0.f), v1 = v0;
        if (hr >= 0 && hr < HH) {
            const float4* p = (const float4*)(in + ((size_t)(b * CIN + c) * HH + hr) * WW + wc * 8);
            v0 = p[0]; v1 = p[1];
        }
        float vals[8] = {v0.x, v0.y, v0.z, v0.w, v1.x, v1.y, v1.z, v1.w};
        const int cb = c >> 3, cl = c & 7;
        #pragma unroll
        for (int k = 0; k < 8; ++k) {
            int wi = wc * 8 + k + 1;
            int slot = cb ^ ((wi + (wi >> 3)) & 7);
            xs[(rr * 82 + wi) * 64 + slot * 8 + cl] = (_Float16)vals[k];
        }
    }
    for (int e = tid; e < 384; e += 128) {
        int wi = (e & 1) ? 81 : 0;
        int rest = e >> 1;
        int c = rest & 63, rr = rest >> 6;
        int slot = (c >> 3) ^ ((wi + (wi >> 3)) & 7);
        xs[(rr * 82 + wi) * 64 + slot * 8 + (c & 7)] = (_Float16)0.f;
    }
    __syncthreads();

    const int wid  = tid >> 6;
    const int lane = tid & 63;
    const int g = lane >> 4, r = lane & 15;
    const int o0 = wid * 16;

    half8 aw[9][2];
    #pragma unroll
    for (int tap = 0; tap < 9; ++tap)
        #pragma unroll
        for (int ch = 0; ch < 2; ++ch)
            aw[tap][ch] = *(const half8*)(W9f + ((tap * 32 + o0 + r) * 64 + ch * 32 + g * 8));
    half8 gaf[2];
    if (src) {
        #pragma unroll
        for (int ch = 0; ch < 2; ++ch)
            gaf[ch] = *(const half8*)(GWf + ((o0 + r) * 64 + ch * 32 + g * 8));
    }

    f32x4 biasv, gbv = {0.f, 0.f, 0.f, 0.f};
    #pragma unroll
    for (int j = 0; j < 4; ++j) biasv[j] = shared_b[o0 + g * 4 + j];
    if (src) {
        #pragma unroll
        for (int j = 0; j < 4; ++j) gbv[j] = g_b[o0 + g * 4 + j];
    }

    for (int ti = 0; ti < 5; ++ti) {
        const int n0 = ti * 16;
        const int wi0 = n0 + r;
        f32x4 accE = biasv;
        f32x4 accO = {0.f, 0.f, 0.f, 0.f};
        f32x4 vacc = gbv;
        #pragma unroll
        for (int tap = 0; tap < 9; ++tap) {
            const int kh = tap / 3, kw = tap % 3;
            const int wi = wi0 + kw;
            const int swz = (wi + (wi >> 3)) & 7;
            #pragma unroll
            for (int ch = 0; ch < 2; ++ch) {
                half8 bf = *(const half8*)(&xs[(kh * 82 + wi) * 64 + (((ch * 4 + g) ^ swz) * 8)]);
                if (tap & 1) accO = __builtin_amdgcn_mfma_f32_16x16x32_f16(aw[tap][ch], bf, accO, 0, 0, 0);
                else         accE = __builtin_amdgcn_mfma_f32_16x16x32_f16(aw[tap][ch], bf, accE, 0, 0, 0);
                if (src && tap == 4)
                    vacc = __builtin_amdgcn_mfma_f32_16x16x32_f16(gaf[ch], bf, vacc, 0, 0, 0);
            }
        }
        const int n = h * WW + n0 + r;
        f32x4 acc;
        #pragma unroll
        for (int j = 0; j < 4; ++j) acc[j] = accE[j] + accO[j];
        half4 pk;
        #pragma unroll
        for (int j = 0; j < 4; ++j) pk[j] = (_Float16)acc[j];
        if (!src) {
            *(half4*)(Q + (size_t)(b * NSP + n) * ICH + o0 + g * 4) = pk;
        } else {
            *(half4*)(K + (size_t)(b * NSP + n) * ICH + o0 + g * 4) = pk;
            #pragma unroll
            for (int j = 0; j < 4; ++j)
                Vt[(size_t)(b * ICH + o0 + g * 4 + j) * NSP + n] = (_Float16)vacc[j];
        }
    }
}

// ---------------------------------------------------------------------------
// Kernel 2: flash attention, register-resident (no LDS/barriers), with FULL
// K+V register double-buffer (loads for it+1 issued before it's compute) and
// 32-row q-tiles (2 fragments -> 2 independent softmax + 4 PV chains).
// S^T = mfma_16x16x32(K,Q): lane(g,r) holds P[q=r][k=kh*16+g*4+j] = B-frag of
// mfma_16x16x16f16; PV consumes it directly from registers.
// grid = 2000 x 64 (one wave per (b, 32-q-tile, k-split)).
// ---------------------------------------------------------------------------
#define ATTN_BODY(IT, KC, VC, KN, VN)                                          \
  {                                                                            \
    const int it_ = (IT);                                                      \
    const int itn_ = (it_ + 1 < NITER) ? it_ + 1 : it_;                        \
    /* prefetch next iteration's K and V tiles into the other buffers */       \
    const _Float16* Kn_ = Kb + (size_t)itn_ * KBLK * ICH;                      \
    _Pragma("unroll")                                                          \
    for (int kh = 0; kh < 4; ++kh)                                             \
      KN[kh] = *(const half8*)(Kn_ + (kh * 16 + r) * ICH + g * 8);             \
    const _Float16* Vn_ = Vb + itn_ * KBLK;                                    \
    _Pragma("unroll")                                                          \
    for (int kh = 0; kh < 4; ++kh)                                             \
      _Pragma("unroll")                                                        \
      for (int ch = 0; ch < 2; ++ch)                                           \
        VN[kh][ch] = *(const half4*)(Vn_ + (size_t)(ch * 16 + r) * NSP + kh * 16 + g * 4); \
    /* compute with current buffers */                                         \
    _Pragma("unroll")                                                          \
    for (int qf = 0; qf < 2; ++qf) {                                           \
      f32x4 sa[4];                                                             \
      _Pragma("unroll")                                                        \
      for (int kh = 0; kh < 4; ++kh)                                           \
        sa[kh] = __builtin_amdgcn_mfma_f32_16x16x32_f16(KC[kh], qa[qf], zero4, 0, 0, 0); \
      float vmax = fmaxf(fmaxf(fmaxf(sa[0][0], sa[0][1]), fmaxf(sa[0][2], sa[0][3])),      \
                         fmaxf(fmaxf(sa[1][0], sa[1][1]), fmaxf(sa[1][2], sa[1][3])));     \
      vmax = fmaxf(vmax, fmaxf(fmaxf(fmaxf(sa[2][0], sa[2][1]), fmaxf(sa[2][2], sa[2][3])),\
                               fmaxf(fmaxf(sa[3][0], sa[3][1]), fmaxf(sa[3][2], sa[3][3]))));\
      if (__any(vmax - m2[qf] > 8.f)) {                                        \
        float tm = vmax;                                                       \
        tm = fmaxf(tm, __shfl_xor(tm, 16));                                    \
        tm = fmaxf(tm, __shfl_xor(tm, 32));                                    \
        float mn = fmaxf(m2[qf], tm);                                          \
        float sc = __expf(m2[qf] - mn);                                        \
        m2[qf] = mn; lp[qf] *= sc;                                             \
        _Pragma("unroll")                                                      \
        for (int j = 0; j < 4; ++j) { yacc[qf][0][j] *= sc; yacc[qf][1][j] *= sc; } \
      }                                                                        \
      half4 pk[4];                                                             \
      _Pragma("unroll")                                                        \
      for (int kh = 0; kh < 4; ++kh) {                                         \
        float ls = 0.f;                                                        \
        _Pragma("unroll")                                                      \
        for (int j = 0; j < 4; ++j) {                                          \
          float p = __expf(sa[kh][j] - m2[qf]);                                \
          ls += p; pk[kh][j] = (_Float16)p;                                    \
        }                                                                      \
        lp[qf] += ls;                                                          \
      }                                                                        \
      _Pragma("unroll")                                                        \
      for (int kh = 0; kh < 4; ++kh)                                           \
        _Pragma("unroll")                                                      \
        for (int ch = 0; ch < 2; ++ch)                                         \
          yacc[qf][ch] = __builtin_amdgcn_mfma_f32_16x16x16f16(                \
              VC[kh][ch], pk[kh], yacc[qf][ch], 0, 0, 0);                      \
    }                                                                          \
  }

__global__ __launch_bounds__(64) void nlb_attn_kernel(
    const _Float16* __restrict__ Q, const _Float16* __restrict__ Km,
    const _Float16* __restrict__ Vt,
    float* __restrict__ YU, float* __restrict__ ML)
{
    const int bid = blockIdx.x;
    const int t = bid % QTILES;                 // fastest: same-split waves march together
    const int rem = bid / QTILES;
    const int b = rem & 1;
    const int s = rem >> 1;                     // slowest
    const int lane = threadIdx.x;
    const int g = lane >> 4, r = lane & 15;

    const _Float16* __restrict__ Qb = Q  + (size_t)b * NSP * ICH;
    const _Float16* __restrict__ Kb = Km + (size_t)b * NSP * ICH + (size_t)s * KRANGE * ICH;
    const _Float16* __restrict__ Vb = Vt + (size_t)b * ICH * NSP + s * KRANGE;

    const f32x4 zero4 = {0.f, 0.f, 0.f, 0.f};

    half8 qa[2];
    #pragma unroll
    for (int qf = 0; qf < 2; ++qf)
        qa[qf] = *(const half8*)(Qb + (size_t)(t * QBLK + qf * 16 + r) * ICH + g * 8);

    f32x4 yacc[2][2];
    float m2[2], lp[2];
    #pragma unroll
    for (int qf = 0; qf < 2; ++qf) {
        yacc[qf][0] = zero4; yacc[qf][1] = zero4;
        m2[qf] = -1e30f; lp[qf] = 0.f;
    }

    half8 kfA[4], kfB[4];
    half4 vfA[4][2], vfB[4][2];
    #pragma unroll
    for (int kh = 0; kh < 4; ++kh) {
        kfA[kh] = *(const half8*)(Kb + (kh * 16 + r) * ICH + g * 8);
        #pragma unroll
        for (int ch = 0; ch < 2; ++ch)
            vfA[kh][ch] = *(const half4*)(Vb + (size_t)(ch * 16 + r) * NSP + kh * 16 + g * 4);
    }

    for (int ith = 0; ith < NITER; ith += 2) {
        ATTN_BODY(ith,     kfA, vfA, kfB, vfB)
        ATTN_BODY(ith + 1, kfB, vfB, kfA, vfA)
    }

    // epilogue: reduce l across the 4 g-copies of each q; write ML + f32 y^T
    #pragma unroll
    for (int qf = 0; qf < 2; ++qf) {
        float lv = lp[qf];
        lv += __shfl_xor(lv, 16);
        lv += __shfl_xor(lv, 32);
        if (g == 0) {
            size_t base = ((size_t)(s * NB + b) * NSP + t * QBLK + qf * 16 + r) * 2;
            ML[base + 0] = m2[qf];
            ML[base + 1] = lv;
        }
        // lane (g,r) holds y[q = t*QBLK + qf*16 + r][d = ch*16 + g*4 + j]
        #pragma unroll
        for (int ch = 0; ch < 2; ++ch)
            *(f32x4*)(YU + ((size_t)(s * NB + b) * NSP + t * QBLK + qf * 16 + r) * ICH
                      + ch * 16 + g * 4) = yacc[qf][ch];
    }
}

// ---------------------------------------------------------------------------
// Kernel 3: combine k-splits, normalize, fused W 1x1 projection + bias +
// residual (round-2 proven verbatim). grid = 200 x 256.
// ---------------------------------------------------------------------------
__global__ __launch_bounds__(256) void nlb_combine_kernel(
    const float* __restrict__ YU, const float* __restrict__ ML,
    const float* __restrict__ W_w, const float* __restrict__ W_b,
    const float* __restrict__ x, float* __restrict__ out)
{
    const int bid = blockIdx.x;
    const int b = bid / 100;
    const int rowbase = (bid % 100) * 64;

    __shared__ float ylds[64][33];
    __shared__ float wwl[CIN * ICH];

    const int tid = threadIdx.x;
    for (int e = tid; e < CIN * ICH; e += 256) wwl[e] = W_w[e];

    #pragma unroll
    for (int i = 0; i < 8; ++i) {
        int idx = tid + i * 256;
        int row = idx >> 5, c = idx & 31;
        int grow = rowbase + row;
        float m[KSPLIT], lv[KSPLIT], M = -1e30f;
        #pragma unroll
        for (int s2 = 0; s2 < KSPLIT; ++s2) {
            size_t base = ((size_t)(s2 * NB + b) * NSP + grow) * 2;
            m[s2]  = ML[base + 0];
            lv[s2] = ML[base + 1];
            M = fmaxf(M, m[s2]);
        }
        float denom = 0.f, acc = 0.f;
        #pragma unroll
        for (int s2 = 0; s2 < KSPLIT; ++s2) {
            float e2 = __expf(m[s2] - M);
            denom += lv[s2] * e2;
            acc += YU[((size_t)(s2 * NB + b) * NSP + grow) * ICH + c] * e2;
        }
        ylds[row][c] = acc / denom;
    }
    __syncthreads();

    const int row = tid & 63;
    const int o0  = tid >> 6;
    #pragma unroll
    for (int k = 0; k < 16; ++k) {
        int o = o0 * 16 + k;
        size_t gi = (size_t)(b * CIN + o) * NSP + rowbase + row;
        float accv = W_b[o] + x[gi];
        #pragma unroll
        for (int c = 0; c < ICH; ++c) accv += wwl[o * ICH + c] * ylds[row][c];
        out[gi] = accv;
    }
}

// ---------------------------------------------------------------------------
extern "C" void kernel_launch(void* const* d_in, const int* in_sizes, int n_in,
                              void* d_out, int out_size, void* d_ws, size_t ws_size,
                              hipStream_t stream) {
    const float* x        = (const float*)d_in[0];
    const float* x_t      = (const float*)d_in[1];
    const float* g_w      = (const float*)d_in[2];
    const float* g_b      = (const float*)d_in[3];
    const float* W_w      = (const float*)d_in[4];
    const float* W_b      = (const float*)d_in[5];
    const float* shared_w = (const float*)d_in[6];
    const float* shared_b = (const float*)d_in[7];
    float* out = (float*)d_out;

    char* ws = (char*)d_ws;
    _Float16* Q   = (_Float16*)(ws);                   //   819,200 B
    _Float16* K   = (_Float16*)(ws + 819200);          //   819,200 B
    _Float16* Vt  = (_Float16*)(ws + 1638400);         //   819,200 B
    float*    YU  = (float*)(ws + 2457600);            // 8,192,000 B (f32 unnormalized)
    float*    ML  = (float*)(ws + 10649600);           //   512,000 B
    _Float16* W9f = (_Float16*)(ws + 11161600);        //    36,864 B
    _Float16* GWf = (_Float16*)(ws + 11198464);        //     4,096 B  (total ~11.2 MB)

    hipLaunchKernelGGL(nlb_prep_kernel, dim3(80), dim3(256), 0, stream,
                       shared_w, g_w, W9f, GWf);
    hipLaunchKernelGGL(nlb_conv_mfma_kernel, dim3(320), dim3(128), 0, stream,
                       x, x_t, W9f, GWf, shared_b, g_b, Q, K, Vt);
    hipLaunchKernelGGL(nlb_attn_kernel, dim3(NB * QTILES * KSPLIT), dim3(64), 0, stream,
                       Q, K, Vt, YU, ML);
    hipLaunchKernelGGL(nlb_combine_kernel, dim3(200), dim3(256), 0, stream,
                       YU, ML, W_w, W_b, x, out);
}

// Round 8
// 67.026 us; speedup vs baseline: 1.8936x; 1.3515x over previous
//
#include <hip/hip_runtime.h>

typedef __attribute__((ext_vector_type(8))) _Float16 half8;
typedef __attribute__((ext_vector_type(4))) _Float16 half4;
typedef __attribute__((ext_vector_type(4))) float f32x4;

#define NB 2
#define CIN 64
#define ICH 32
#define HH 80
#define WW 80
#define NSP 6400
#define KSPLIT 5
#define KRANGE 1280
#define KBLK 64
#define NITER 20
#define QBLK 32
#define QGROUPS 50   /* 128 q-rows per block */

// ---------------------------------------------------------------------------
// Kernel 0: weight prep. W9f[tap][o][c] f16, GWf[o][c] f16.
// ---------------------------------------------------------------------------
__global__ __launch_bounds__(256) void nlb_prep_kernel(
    const float* __restrict__ shared_w, const float* __restrict__ g_w,
    _Float16* __restrict__ W9f, _Float16* __restrict__ GWf)
{
    int e = blockIdx.x * 256 + threadIdx.x;
    if (e < 9 * 32 * 64) {
        int c = e & 63, o = (e >> 6) & 31, tap = e >> 11;
        W9f[e] = (_Float16)shared_w[(o * 64 + c) * 9 + tap];
    } else {
        int e2 = e - 9 * 32 * 64;
        GWf[e2] = (_Float16)g_w[e2];
    }
}

// ---------------------------------------------------------------------------
// Kernel 1: implicit-GEMM 3x3 conv via MFMA + fused 1x1 g-conv (round-2 proven).
// ---------------------------------------------------------------------------
__global__ __launch_bounds__(128) void nlb_conv_mfma_kernel(
    const float* __restrict__ x, const float* __restrict__ x_t,
    const _Float16* __restrict__ W9f, const _Float16* __restrict__ GWf,
    const float* __restrict__ shared_b, const float* __restrict__ g_b,
    _Float16* __restrict__ Q, _Float16* __restrict__ K, _Float16* __restrict__ Vt)
{
    const int bid = blockIdx.x;
    const int src = bid & 1;
    const int b   = (bid >> 1) & 1;
    const int h   = bid >> 2;
    const float* __restrict__ in = src ? x_t : x;

    __shared__ _Float16 xs[3 * 82 * 64];

    const int tid = threadIdx.x;

    #pragma unroll
    for (int i = 0; i < 15; ++i) {
        int idx = tid + i * 128;
        int wc = idx % 10;
        int c  = (idx / 10) & 63;
        int rr = idx / 640;
        int hr = h + rr - 1;
        float4 v0 = make_float4(0.f, 0.f, 0.f, 0.f), v1 = v0;
        if (hr >= 0 && hr < HH) {
            const float4* p = (const float4*)(in + ((size_t)(b * CIN + c) * HH + hr) * WW + wc * 8);
            v0 = p[0]; v1 = p[1];
        }
        float vals[8] = {v0.x, v0.y, v0.z, v0.w, v1.x, v1.y, v1.z, v1.w};
        const int cb = c >> 3, cl = c & 7;
        #pragma unroll
        for (int k = 0; k < 8; ++k) {
            int wi = wc * 8 + k + 1;
            int slot = cb ^ ((wi + (wi >> 3)) & 7);
            xs[(rr * 82 + wi) * 64 + slot * 8 + cl] = (_Float16)vals[k];
        }
    }
    for (int e = tid; e < 384; e += 128) {
        int wi = (e & 1) ? 81 : 0;
        int rest = e >> 1;
        int c = rest & 63, rr = rest >> 6;
        int slot = (c >> 3) ^ ((wi + (wi >> 3)) & 7);
        xs[(rr * 82 + wi) * 64 + slot * 8 + (c & 7)] = (_Float16)0.f;
    }
    __syncthreads();

    const int wid  = tid >> 6;
    const int lane = tid & 63;
    const int g = lane >> 4, r = lane & 15;
    const int o0 = wid * 16;

    half8 aw[9][2];
    #pragma unroll
    for (int tap = 0; tap < 9; ++tap)
        #pragma unroll
        for (int ch = 0; ch < 2; ++ch)
            aw[tap][ch] = *(const half8*)(W9f + ((tap * 32 + o0 + r) * 64 + ch * 32 + g * 8));
    half8 gaf[2];
    if (src) {
        #pragma unroll
        for (int ch = 0; ch < 2; ++ch)
            gaf[ch] = *(const half8*)(GWf + ((o0 + r) * 64 + ch * 32 + g * 8));
    }

    f32x4 biasv, gbv = {0.f, 0.f, 0.f, 0.f};
    #pragma unroll
    for (int j = 0; j < 4; ++j) biasv[j] = shared_b[o0 + g * 4 + j];
    if (src) {
        #pragma unroll
        for (int j = 0; j < 4; ++j) gbv[j] = g_b[o0 + g * 4 + j];
    }

    for (int ti = 0; ti < 5; ++ti) {
        const int n0 = ti * 16;
        const int wi0 = n0 + r;
        f32x4 accE = biasv;
        f32x4 accO = {0.f, 0.f, 0.f, 0.f};
        f32x4 vacc = gbv;
        #pragma unroll
        for (int tap = 0; tap < 9; ++tap) {
            const int kh = tap / 3, kw = tap % 3;
            const int wi = wi0 + kw;
            const int swz = (wi + (wi >> 3)) & 7;
            #pragma unroll
            for (int ch = 0; ch < 2; ++ch) {
                half8 bf = *(const half8*)(&xs[(kh * 82 + wi) * 64 + (((ch * 4 + g) ^ swz) * 8)]);
                if (tap & 1) accO = __builtin_amdgcn_mfma_f32_16x16x32_f16(aw[tap][ch], bf, accO, 0, 0, 0);
                else         accE = __builtin_amdgcn_mfma_f32_16x16x32_f16(aw[tap][ch], bf, accE, 0, 0, 0);
                if (src && tap == 4)
                    vacc = __builtin_amdgcn_mfma_f32_16x16x32_f16(gaf[ch], bf, vacc, 0, 0, 0);
            }
        }
        const int n = h * WW + n0 + r;
        f32x4 acc;
        #pragma unroll
        for (int j = 0; j < 4; ++j) acc[j] = accE[j] + accO[j];
        half4 pk;
        #pragma unroll
        for (int j = 0; j < 4; ++j) pk[j] = (_Float16)acc[j];
        if (!src) {
            *(half4*)(Q + (size_t)(b * NSP + n) * ICH + o0 + g * 4) = pk;
        } else {
            *(half4*)(K + (size_t)(b * NSP + n) * ICH + o0 + g * 4) = pk;
            #pragma unroll
            for (int j = 0; j < 4; ++j)
                Vt[(size_t)(b * ICH + o0 + g * 4 + j) * NSP + n] = (_Float16)vacc[j];
        }
    }
}

// ---------------------------------------------------------------------------
// Kernel 2: flash attention. 4 waves/block share double-buffered LDS K/V tiles
// (cooperative coalesced staging: 2x16B global loads per thread per iter);
// each wave owns a 32-row q-tile. P stays in registers (verified K=16 PV:
// S^T = mfma_16x16x32(K,Q) -> lane(g,r) holds P[q=r][k=kh*16+g*4+j] = B-frag
// of mfma_16x16x16f16). One barrier per iteration.
// grid = 500 x 256 (b x 50 q-groups x 5 k-splits).
// ---------------------------------------------------------------------------
#define KPAD 40   /* K LDS row: 80 B  (2-way max on b128 reads) */
#define VPAD 72   /* V LDS row: 144 B (4-way max on b64 reads)  */

__global__ __launch_bounds__(256) void nlb_attn_kernel(
    const _Float16* __restrict__ Q, const _Float16* __restrict__ Km,
    const _Float16* __restrict__ Vt,
    float* __restrict__ YU, float* __restrict__ ML)
{
    const int bid = blockIdx.x;
    const int tg  = bid % QGROUPS;
    const int rem = bid / QGROUPS;
    const int b = rem & 1;
    const int s = rem >> 1;

    const int tid  = threadIdx.x;
    const int wid  = tid >> 6;
    const int lane = tid & 63;
    const int g = lane >> 4, r = lane & 15;

    __shared__ __align__(16) _Float16 Kls[2][KBLK][KPAD];
    __shared__ __align__(16) _Float16 Vls[2][ICH][VPAD];

    const _Float16* __restrict__ Qb = Q  + (size_t)b * NSP * ICH;
    const _Float16* __restrict__ Kb = Km + (size_t)b * NSP * ICH + (size_t)s * KRANGE * ICH;
    const _Float16* __restrict__ Vb = Vt + (size_t)b * ICH * NSP + s * KRANGE;

    const f32x4 zero4 = {0.f, 0.f, 0.f, 0.f};

    const int q0 = tg * 128 + wid * QBLK;
    half8 qa[2];
    #pragma unroll
    for (int qf = 0; qf < 2; ++qf)
        qa[qf] = *(const half8*)(Qb + (size_t)(q0 + qf * 16 + r) * ICH + g * 8);

    f32x4 yacc[2][2];
    float m2[2], lp[2];
    #pragma unroll
    for (int qf = 0; qf < 2; ++qf) {
        yacc[qf][0] = zero4; yacc[qf][1] = zero4;
        m2[qf] = -1e30f; lp[qf] = 0.f;
    }

    // staging assignments (per thread, 16B each)
    const int krow = tid >> 2, kcb = tid & 3;   // K tile: 64 rows x 4 blocks
    const int vrow = tid >> 3, vcb = tid & 7;   // V tile: 32 rows x 8 blocks

    // prologue: stage tile 0 into buffer 0
    {
        half8 k0 = *(const half8*)(Kb + (size_t)krow * ICH + kcb * 8);
        half8 v0 = *(const half8*)(Vb + (size_t)vrow * NSP + vcb * 8);
        *(half8*)(&Kls[0][krow][kcb * 8]) = k0;
        *(half8*)(&Vls[0][vrow][vcb * 8]) = v0;
    }
    __syncthreads();

    int cur = 0;
    for (int it = 0; it < NITER; ++it) {
        const bool more = (it + 1 < NITER);
        // issue next tile's global loads early (latency hides under compute)
        half8 kst, vst;
        if (more) {
            kst = *(const half8*)(Kb + (size_t)(it + 1) * KBLK * ICH + (size_t)krow * ICH + kcb * 8);
            vst = *(const half8*)(Vb + (size_t)((it + 1) * KBLK) + (size_t)vrow * NSP + vcb * 8);
        }

        // fragments from LDS
        half8 kf[4];
        #pragma unroll
        for (int kh = 0; kh < 4; ++kh)
            kf[kh] = *(const half8*)(&Kls[cur][kh * 16 + r][g * 8]);
        half4 vf[4][2];
        #pragma unroll
        for (int kh = 0; kh < 4; ++kh)
            #pragma unroll
            for (int ch = 0; ch < 2; ++ch)
                vf[kh][ch] = *(const half4*)(&Vls[cur][ch * 16 + r][kh * 16 + g * 4]);

        #pragma unroll
        for (int qf = 0; qf < 2; ++qf) {
            f32x4 sa[4];
            #pragma unroll
            for (int kh = 0; kh < 4; ++kh)
                sa[kh] = __builtin_amdgcn_mfma_f32_16x16x32_f16(kf[kh], qa[qf], zero4, 0, 0, 0);
            float vmax = fmaxf(fmaxf(fmaxf(sa[0][0], sa[0][1]), fmaxf(sa[0][2], sa[0][3])),
                               fmaxf(fmaxf(sa[1][0], sa[1][1]), fmaxf(sa[1][2], sa[1][3])));
            vmax = fmaxf(vmax, fmaxf(fmaxf(fmaxf(sa[2][0], sa[2][1]), fmaxf(sa[2][2], sa[2][3])),
                                     fmaxf(fmaxf(sa[3][0], sa[3][1]), fmaxf(sa[3][2], sa[3][3]))));
            if (__any(vmax - m2[qf] > 8.f)) {
                float tm = vmax;
                tm = fmaxf(tm, __shfl_xor(tm, 16));
                tm = fmaxf(tm, __shfl_xor(tm, 32));
                float mn = fmaxf(m2[qf], tm);
                float sc = __expf(m2[qf] - mn);
                m2[qf] = mn; lp[qf] *= sc;
                #pragma unroll
                for (int j = 0; j < 4; ++j) { yacc[qf][0][j] *= sc; yacc[qf][1][j] *= sc; }
            }
            half4 pk[4];
            #pragma unroll
            for (int kh = 0; kh < 4; ++kh) {
                float ls = 0.f;
                #pragma unroll
                for (int j = 0; j < 4; ++j) {
                    float p = __expf(sa[kh][j] - m2[qf]);
                    ls += p; pk[kh][j] = (_Float16)p;
                }
                lp[qf] += ls;
            }
            #pragma unroll
            for (int kh = 0; kh < 4; ++kh)
                #pragma unroll
                for (int ch = 0; ch < 2; ++ch)
                    yacc[qf][ch] = __builtin_amdgcn_mfma_f32_16x16x16f16(
                        vf[kh][ch], pk[kh], yacc[qf][ch], 0, 0, 0);
        }

        // write next buffer, then barrier
        if (more) {
            *(half8*)(&Kls[cur ^ 1][krow][kcb * 8]) = kst;
            *(half8*)(&Vls[cur ^ 1][vrow][vcb * 8]) = vst;
        }
        __syncthreads();
        cur ^= 1;
    }

    // epilogue: reduce l across the 4 g-copies of each q; write ML + f32 y^T
    #pragma unroll
    for (int qf = 0; qf < 2; ++qf) {
        float lv = lp[qf];
        lv += __shfl_xor(lv, 16);
        lv += __shfl_xor(lv, 32);
        if (g == 0) {
            size_t base = ((size_t)(s * NB + b) * NSP + q0 + qf * 16 + r) * 2;
            ML[base + 0] = m2[qf];
            ML[base + 1] = lv;
        }
        // lane (g,r) holds y[q = q0 + qf*16 + r][d = ch*16 + g*4 + j]
        #pragma unroll
        for (int ch = 0; ch < 2; ++ch)
            *(f32x4*)(YU + ((size_t)(s * NB + b) * NSP + q0 + qf * 16 + r) * ICH
                      + ch * 16 + g * 4) = yacc[qf][ch];
    }
}

// ---------------------------------------------------------------------------
// Kernel 3: combine k-splits, normalize, fused W 1x1 projection + bias +
// residual (round-2 proven verbatim). grid = 200 x 256.
// ---------------------------------------------------------------------------
__global__ __launch_bounds__(256) void nlb_combine_kernel(
    const float* __restrict__ YU, const float* __restrict__ ML,
    const float* __restrict__ W_w, const float* __restrict__ W_b,
    const float* __restrict__ x, float* __restrict__ out)
{
    const int bid = blockIdx.x;
    const int b = bid / 100;
    const int rowbase = (bid % 100) * 64;

    __shared__ float ylds[64][33];
    __shared__ float wwl[CIN * ICH];

    const int tid = threadIdx.x;
    for (int e = tid; e < CIN * ICH; e += 256) wwl[e] = W_w[e];

    #pragma unroll
    for (int i = 0; i < 8; ++i) {
        int idx = tid + i * 256;
        int row = idx >> 5, c = idx & 31;
        int grow = rowbase + row;
        float m[KSPLIT], lv[KSPLIT], M = -1e30f;
        #pragma unroll
        for (int s2 = 0; s2 < KSPLIT; ++s2) {
            size_t base = ((size_t)(s2 * NB + b) * NSP + grow) * 2;
            m[s2]  = ML[base + 0];
            lv[s2] = ML[base + 1];
            M = fmaxf(M, m[s2]);
        }
        float denom = 0.f, acc = 0.f;
        #pragma unroll
        for (int s2 = 0; s2 < KSPLIT; ++s2) {
            float e2 = __expf(m[s2] - M);
            denom += lv[s2] * e2;
            acc += YU[((size_t)(s2 * NB + b) * NSP + grow) * ICH + c] * e2;
        }
        ylds[row][c] = acc / denom;
    }
    __syncthreads();

    const int row = tid & 63;
    const int o0  = tid >> 6;
    #pragma unroll
    for (int k = 0; k < 16; ++k) {
        int o = o0 * 16 + k;
        size_t gi = (size_t)(b * CIN + o) * NSP + rowbase + row;
        float accv = W_b[o] + x[gi];
        #pragma unroll
        for (int c = 0; c < ICH; ++c) accv += wwl[o * ICH + c] * ylds[row][c];
        out[gi] = accv;
    }
}

// ---------------------------------------------------------------------------
extern "C" void kernel_launch(void* const* d_in, const int* in_sizes, int n_in,
                              void* d_out, int out_size, void* d_ws, size_t ws_size,
                              hipStream_t stream) {
    const float* x        = (const float*)d_in[0];
    const float* x_t      = (const float*)d_in[1];
    const float* g_w      = (const float*)d_in[2];
    const float* g_b      = (const float*)d_in[3];
    const float* W_w      = (const float*)d_in[4];
    const float* W_b      = (const float*)d_in[5];
    const float* shared_w = (const float*)d_in[6];
    const float* shared_b = (const float*)d_in[7];
    float* out = (float*)d_out;

    char* ws = (char*)d_ws;
    _Float16* Q   = (_Float16*)(ws);                   //   819,200 B
    _Float16* K   = (_Float16*)(ws + 819200);          //   819,200 B
    _Float16* Vt  = (_Float16*)(ws + 1638400);         //   819,200 B
    float*    YU  = (float*)(ws + 2457600);            // 8,192,000 B (f32 unnormalized)
    float*    ML  = (float*)(ws + 10649600);           //   512,000 B
    _Float16* W9f = (_Float16*)(ws + 11161600);        //    36,864 B
    _Float16* GWf = (_Float16*)(ws + 11198464);        //     4,096 B  (total ~11.2 MB)

    hipLaunchKernelGGL(nlb_prep_kernel, dim3(80), dim3(256), 0, stream,
                       shared_w, g_w, W9f, GWf);
    hipLaunchKernelGGL(nlb_conv_mfma_kernel, dim3(320), dim3(128), 0, stream,
                       x, x_t, W9f, GWf, shared_b, g_b, Q, K, Vt);
    hipLaunchKernelGGL(nlb_attn_kernel, dim3(NB * QGROUPS * KSPLIT), dim3(256), 0, stream,
                       Q, K, Vt, YU, ML);
    hipLaunchKernelGGL(nlb_combine_kernel, dim3(200), dim3(256), 0, stream,
                       YU, ML, W_w, W_b, x, out);
}